// Round 5
// baseline (236.306 us; speedup 1.0000x reference)
//
#include <hip/hip_runtime.h>

// ReactDiffDynamics: dUdt = a*lap(U) + U - U^3 - k - V ; dVdt = b*lap(V) + U - V
// Periodic 5-point Laplacian (jnp.roll semantics), B=64, H=W=512, fp32.
//
// Counters (v3/v4): HBM 32%, VALU 12%, occ 77%, LDS 0 -> nothing saturated;
// ~90 cycles per vmem inst => bound by outstanding-miss capacity (reads hit
// L3, ~300ns, limited lines in flight per CU).
//
// v5: vertical register blocking — each thread computes 2 stacked rows
// (h, h+1) of its float4 column. Rows h-1..h+2 loaded once: 4 row-loads per
// channel for 2 output rows (vs 3 per 1 row before) => read-request traffic
// x0.67 AND 8 independent loads in flight per wave (vs 6) — both attack the
// miss-queue bound. No serial dependence (unlike v2's rolling walk).
// W/E halo via wave shuffle (lane 0/63 fix up with 2-active-lane loads).
// Natural block order (XCD swizzle measured as small net negative; L3 absorbs
// cross-XCD halo reuse — FETCH 65MB << 128MB input). Plain float4 stores.

constexpr int B = 64;
constexpr int H = 512;
constexpr int W = 512;
constexpr int W4 = W / 4;            // 128 float4 groups per row
constexpr int HP = H / 2;            // 256 row-pairs per image
constexpr int PLANE = H * W;
constexpr int GRID = B * HP * W4 / 256;  // 8192 blocks

__global__ __launch_bounds__(256) void react_diff_kernel(
    const float* __restrict__ x,       // (B, 2, H, W)
    const float* __restrict__ params,  // (B, 3)
    float* __restrict__ out)           // (B, 2, H, W)
{
    const float inv_dx2 = 240.25f;     // 1/dx^2, dx = 2/31

    const int tid  = blockIdx.x * 256 + (int)threadIdx.x;  // [0, B*HP*W4)
    const int lane = threadIdx.x & 63;
    const int wv   = tid & (W4 - 1);
    const int rem  = tid >> 7;          // global row-pair index
    const int hp   = rem & (HP - 1);
    const int b    = rem >> 8;          // block-uniform
    const int h    = hp << 1;           // even row of the pair

    const int hn = (hp == 0)      ? H - 1 : h - 1;   // north of row h
    const int hs = (hp == HP - 1) ? 0     : h + 2;   // south of row h+1
    const int w0 = wv * 4;
    const int wW = (wv == 0)      ? W - 1 : w0 - 1;  // west wrap column
    const int wE = (wv == W4 - 1) ? 0     : w0 + 4;  // east wrap column

    const float* Ub = x + (size_t)b * 2 * PLANE;
    const float* Vb = Ub + PLANE;

    const size_t rn = (size_t)hn * W;
    const size_t r0 = (size_t)h  * W;
    const size_t r1 = r0 + W;
    const size_t rs = (size_t)hs * W;

    // 8 independent float4 loads — all issued before any use
    float4 Un = ((const float4*)(Ub + rn))[wv];
    float4 U0 = ((const float4*)(Ub + r0))[wv];
    float4 U1 = ((const float4*)(Ub + r1))[wv];
    float4 Us = ((const float4*)(Ub + rs))[wv];
    float4 Vn = ((const float4*)(Vb + rn))[wv];
    float4 V0 = ((const float4*)(Vb + r0))[wv];
    float4 V1 = ((const float4*)(Vb + r1))[wv];
    float4 Vs = ((const float4*)(Vb + rs))[wv];

    // W/E halo from neighbor lanes' registers
    float Uw0 = __shfl_up(U0.w, 1);
    float Uw1 = __shfl_up(U1.w, 1);
    float Vw0 = __shfl_up(V0.w, 1);
    float Vw1 = __shfl_up(V1.w, 1);
    float Ue0 = __shfl_down(U0.x, 1);
    float Ue1 = __shfl_down(U1.x, 1);
    float Ve0 = __shfl_down(V0.x, 1);
    float Ve1 = __shfl_down(V1.x, 1);
    if (lane == 0 || lane == 63) {
        const int off = (lane == 0) ? wW : wE;   // border column for this lane
        const float u0 = Ub[r0 + off];
        const float u1 = Ub[r1 + off];
        const float v0 = Vb[r0 + off];
        const float v1 = Vb[r1 + off];
        if (lane == 0) { Uw0 = u0; Uw1 = u1; Vw0 = v0; Vw1 = v1; }
        else           { Ue0 = u0; Ue1 = u1; Ve0 = v0; Ve1 = v1; }
    }

    // block-uniform -> scalar loads
    const float ca = params[b * 3 + 0] * inv_dx2;
    const float cb = params[b * 3 + 1] * inv_dx2;
    const float pk = params[b * 3 + 2];

    float4 lap, d;
    float* ob = out + (size_t)b * 2 * PLANE;

    // ---- row h (neighbors Un, U1) ----
    lap.x = Un.x + U1.x + Uw0  + U0.y - 4.0f * U0.x;
    lap.y = Un.y + U1.y + U0.x + U0.z - 4.0f * U0.y;
    lap.z = Un.z + U1.z + U0.y + U0.w - 4.0f * U0.z;
    lap.w = Un.w + U1.w + U0.z + Ue0  - 4.0f * U0.w;
    d.x = ca * lap.x + U0.x - U0.x * U0.x * U0.x - pk - V0.x;
    d.y = ca * lap.y + U0.y - U0.y * U0.y * U0.y - pk - V0.y;
    d.z = ca * lap.z + U0.z - U0.z * U0.z * U0.z - pk - V0.z;
    d.w = ca * lap.w + U0.w - U0.w * U0.w * U0.w - pk - V0.w;
    ((float4*)(ob + r0))[wv] = d;

    lap.x = Vn.x + V1.x + Vw0  + V0.y - 4.0f * V0.x;
    lap.y = Vn.y + V1.y + V0.x + V0.z - 4.0f * V0.y;
    lap.z = Vn.z + V1.z + V0.y + V0.w - 4.0f * V0.z;
    lap.w = Vn.w + V1.w + V0.z + Ve0  - 4.0f * V0.w;
    d.x = cb * lap.x + U0.x - V0.x;
    d.y = cb * lap.y + U0.y - V0.y;
    d.z = cb * lap.z + U0.z - V0.z;
    d.w = cb * lap.w + U0.w - V0.w;
    ((float4*)(ob + PLANE + r0))[wv] = d;

    // ---- row h+1 (neighbors U0, Us) ----
    lap.x = U0.x + Us.x + Uw1  + U1.y - 4.0f * U1.x;
    lap.y = U0.y + Us.y + U1.x + U1.z - 4.0f * U1.y;
    lap.z = U0.z + Us.z + U1.y + U1.w - 4.0f * U1.z;
    lap.w = U0.w + Us.w + U1.z + Ue1  - 4.0f * U1.w;
    d.x = ca * lap.x + U1.x - U1.x * U1.x * U1.x - pk - V1.x;
    d.y = ca * lap.y + U1.y - U1.y * U1.y * U1.y - pk - V1.y;
    d.z = ca * lap.z + U1.z - U1.z * U1.z * U1.z - pk - V1.z;
    d.w = ca * lap.w + U1.w - U1.w * U1.w * U1.w - pk - V1.w;
    ((float4*)(ob + r1))[wv] = d;

    lap.x = V0.x + Vs.x + Vw1  + V1.y - 4.0f * V1.x;
    lap.y = V0.y + Vs.y + V1.x + V1.z - 4.0f * V1.y;
    lap.z = V0.z + Vs.z + V1.y + V1.w - 4.0f * V1.z;
    lap.w = V0.w + Vs.w + V1.z + Ve1  - 4.0f * V1.w;
    d.x = cb * lap.x + U1.x - V1.x;
    d.y = cb * lap.y + U1.y - V1.y;
    d.z = cb * lap.z + U1.z - V1.z;
    d.w = cb * lap.w + U1.w - V1.w;
    ((float4*)(ob + PLANE + r1))[wv] = d;
}

extern "C" void kernel_launch(void* const* d_in, const int* in_sizes, int n_in,
                              void* d_out, int out_size, void* d_ws, size_t ws_size,
                              hipStream_t stream) {
    // d_in[0] = t (1 float, unused), d_in[1] = x (B,2,H,W), d_in[2] = params (B,3)
    const float* x      = (const float*)d_in[1];
    const float* params = (const float*)d_in[2];
    float* out          = (float*)d_out;

    react_diff_kernel<<<GRID, 256, 0, stream>>>(x, params, out);
}

// Round 6
// 234.776 us; speedup vs baseline: 1.0065x; 1.0065x over previous
//
#include <hip/hip_runtime.h>

// ReactDiffDynamics: dUdt = a*lap(U) + U - U^3 - k - V ; dVdt = b*lap(V) + U - V
// Periodic 5-point Laplacian (jnp.roll semantics), B=64, H=W=512, fp32.
//
// v6: LDS band tiling. Evidence: v1/v4/v5 all ~70-78us at HBM 32%, VALU 12%,
// occ 77% -> bound by cache-line requests in flight (reads served by L3 at
// ~350ns, per-CU outstanding-line queue caps effective BW at ~2.7 TB/s while
// pure-write fill hits 6.7 TB/s). v5 halved instructions but not line
// requests -> no gain. v6 cuts global line requests ~2.8x:
//   each block stages rows h0-1..h0+8 (10 rows x 2 channels, 40 KB LDS) with
//   10 independent float4 streaming loads/thread (deep MLP, one barrier),
//   then computes 8 rows/channel from LDS. Read amplification 10/8 = 1.25.
//   W/E halo = shifted ds_read_b128 (conflict-free). Stores unchanged.
// 4096 blocks, 4 blocks/CU (LDS-bound: 40KB of 160KB), natural block order.

constexpr int B = 64;
constexpr int H = 512;
constexpr int W = 512;
constexpr int W4 = W / 4;            // 128 float4 groups per row
constexpr int PLANE = H * W;
constexpr int TR = 8;                // output rows per block
constexpr int LR = TR + 2;           // staged rows per channel (with halo)
constexpr int TILES = H / TR;        // 64 tiles per image
constexpr int GRID = B * TILES;      // 4096 blocks

__global__ __launch_bounds__(256) void react_diff_kernel(
    const float* __restrict__ x,       // (B, 2, H, W)
    const float* __restrict__ params,  // (B, 3)
    float* __restrict__ out)           // (B, 2, H, W)
{
    __shared__ float lds[2][LR][W];    // 40 KB

    const float inv_dx2 = 240.25f;     // 1/dx^2, dx = 2/31

    const int t     = threadIdx.x;
    const int c     = t & (W4 - 1);    // float4 column [0,128)
    const int rhalf = t >> 7;          // 0/1: which row of each staged pair
    const int tile  = blockIdx.x;
    const int b     = tile >> 6;       // tile / TILES   (block-uniform)
    const int trow  = tile & (TILES - 1);
    const int h0    = trow * TR;

    const float* Ub = x + (size_t)b * 2 * PLANE;
    const float* Vb = Ub + PLANE;

    // ---- stage: 10 independent float4 loads per thread, then LDS writes ----
    // thread t stages LDS rows {2k + rhalf}, k=0..4, at column c, both channels.
    float4 tU[5], tV[5];
    #pragma unroll
    for (int k = 0; k < 5; ++k) {
        const int r  = 2 * k + rhalf;              // LDS row 0..9
        const int gr = (h0 - 1 + r) & (H - 1);     // global row (periodic)
        tU[k] = ((const float4*)(Ub + (size_t)gr * W))[c];
        tV[k] = ((const float4*)(Vb + (size_t)gr * W))[c];
    }
    #pragma unroll
    for (int k = 0; k < 5; ++k) {
        const int r = 2 * k + rhalf;
        *(float4*)&lds[0][r][c * 4] = tU[k];
        *(float4*)&lds[1][r][c * 4] = tV[k];
    }
    __syncthreads();

    // block-uniform -> scalar loads
    const float ca = params[b * 3 + 0] * inv_dx2;
    const float cb = params[b * 3 + 1] * inv_dx2;
    const float pk = params[b * 3 + 2];

    float* oU = out + (size_t)b * 2 * PLANE;
    float* oV = oU + PLANE;

    const int cW = (c - 1) & (W4 - 1);  // periodic west/east f4 columns
    const int cE = (c + 1) & (W4 - 1);

    // ---- compute: 4 row-pair iterations, 8 rows total, all from LDS ----
    #pragma unroll
    for (int it = 0; it < 4; ++it) {
        const int lr = 2 * it + rhalf;        // output row within tile, 0..7
        const size_t ro = (size_t)(h0 + lr) * W;

        // LDS rows: north = lr, center = lr+1, south = lr+2
        float4 Un = *(const float4*)&lds[0][lr    ][c  * 4];
        float4 Uc = *(const float4*)&lds[0][lr + 1][c  * 4];
        float4 Us = *(const float4*)&lds[0][lr + 2][c  * 4];
        float4 UL = *(const float4*)&lds[0][lr + 1][cW * 4];
        float4 UR = *(const float4*)&lds[0][lr + 1][cE * 4];

        float4 Vn = *(const float4*)&lds[1][lr    ][c  * 4];
        float4 Vc = *(const float4*)&lds[1][lr + 1][c  * 4];
        float4 Vs = *(const float4*)&lds[1][lr + 2][c  * 4];
        float4 VL = *(const float4*)&lds[1][lr + 1][cW * 4];
        float4 VR = *(const float4*)&lds[1][lr + 1][cE * 4];

        float4 lap, d;

        lap.x = Un.x + Us.x + UL.w + Uc.y - 4.0f * Uc.x;
        lap.y = Un.y + Us.y + Uc.x + Uc.z - 4.0f * Uc.y;
        lap.z = Un.z + Us.z + Uc.y + Uc.w - 4.0f * Uc.z;
        lap.w = Un.w + Us.w + Uc.z + UR.x - 4.0f * Uc.w;
        d.x = ca * lap.x + Uc.x - Uc.x * Uc.x * Uc.x - pk - Vc.x;
        d.y = ca * lap.y + Uc.y - Uc.y * Uc.y * Uc.y - pk - Vc.y;
        d.z = ca * lap.z + Uc.z - Uc.z * Uc.z * Uc.z - pk - Vc.z;
        d.w = ca * lap.w + Uc.w - Uc.w * Uc.w * Uc.w - pk - Vc.w;
        ((float4*)(oU + ro))[c] = d;

        lap.x = Vn.x + Vs.x + VL.w + Vc.y - 4.0f * Vc.x;
        lap.y = Vn.y + Vs.y + Vc.x + Vc.z - 4.0f * Vc.y;
        lap.z = Vn.z + Vs.z + Vc.y + Vc.w - 4.0f * Vc.z;
        lap.w = Vn.w + Vs.w + Vc.z + VR.x - 4.0f * Vc.w;
        d.x = cb * lap.x + Uc.x - Vc.x;
        d.y = cb * lap.y + Uc.y - Vc.y;
        d.z = cb * lap.z + Uc.z - Vc.z;
        d.w = cb * lap.w + Uc.w - Vc.w;
        ((float4*)(oV + ro))[c] = d;
    }
}

extern "C" void kernel_launch(void* const* d_in, const int* in_sizes, int n_in,
                              void* d_out, int out_size, void* d_ws, size_t ws_size,
                              hipStream_t stream) {
    // d_in[0] = t (1 float, unused), d_in[1] = x (B,2,H,W), d_in[2] = params (B,3)
    const float* x      = (const float*)d_in[1];
    const float* params = (const float*)d_in[2];
    float* out          = (float*)d_out;

    react_diff_kernel<<<GRID, 256, 0, stream>>>(x, params, out);
}